// Round 4
// baseline (949.391 us; speedup 1.0000x reference)
//
#include <hip/hip_runtime.h>

// Problem constants
#define DM     1024
#define NHEADS 16
#define DK     64
#define NB     8
#define SEQ    1024
#define MROWS  (NB * SEQ)          // 8192
#define NQ     ((size_t)MROWS * DM)  // 8M elements

typedef __attribute__((ext_vector_type(8))) __bf16 bf16x8;
typedef __attribute__((ext_vector_type(8))) short  short8v;
typedef __attribute__((ext_vector_type(4))) float  f32x4;

typedef const __attribute__((address_space(1))) void* gas_ptr;
typedef __attribute__((address_space(3))) void*       las_ptr;

__device__ __forceinline__ void load_lds16(const void* g, void* l) {
    __builtin_amdgcn_global_load_lds((gas_ptr)g, (las_ptr)l, 16, 0, 0);
}

__device__ __forceinline__ unsigned short bf16_rne(float x) {
    unsigned int u = __float_as_uint(x);
    u += 0x7FFFu + ((u >> 16) & 1u);
    return (unsigned short)(u >> 16);
}

// ---------------------------------------------------------------------------
// conv_split: fp32 array -> bf16 hi + bf16 lo (RNE; lo = rne(x - hi)).
// 8 elements/thread, fully vectorized. N must be multiple of 2048.
// ---------------------------------------------------------------------------
__global__ __launch_bounds__(256)
void conv_split(const float* __restrict__ in, unsigned short* __restrict__ hi,
                unsigned short* __restrict__ lo)
{
    size_t i8 = ((size_t)blockIdx.x * 256 + threadIdx.x) * 8;
    float4 x0 = *(const float4*)(in + i8);
    float4 x1 = *(const float4*)(in + i8 + 4);
    float xs[8] = {x0.x, x0.y, x0.z, x0.w, x1.x, x1.y, x1.z, x1.w};
    short8v vh, vl;
#pragma unroll
    for (int j = 0; j < 8; ++j) {
        unsigned short h = bf16_rne(xs[j]);
        float hf = __uint_as_float((unsigned int)h << 16);
        unsigned short l = bf16_rne(xs[j] - hf);
        vh[j] = (short)h;
        vl[j] = (short)l;
    }
    *(short8v*)(hi + i8) = vh;
    *(short8v*)(lo + i8) = vl;
}

// ---------------------------------------------------------------------------
// conv_w: W [1024 k][1024 n] fp32 -> Wt_hi/lo [n][k] bf16 (transposed split).
// grid (n-tiles=16, k-tiles=32, w=4). 64n x 32k tile via LDS.
// ---------------------------------------------------------------------------
__global__ __launch_bounds__(256)
void conv_w(const float* __restrict__ W0, const float* __restrict__ W1,
            const float* __restrict__ W2, const float* __restrict__ W3,
            unsigned short* __restrict__ hiB, unsigned short* __restrict__ loB)
{
    __shared__ float Wf[32][68];
    const int t = threadIdx.x;
    const int n0 = blockIdx.x * 64, k0 = blockIdx.y * 32, z = blockIdx.z;
    const float* W = (z == 0) ? W0 : (z == 1) ? W1 : (z == 2) ? W2 : W3;
    unsigned short* hi = hiB + (size_t)z * DM * DM;
    unsigned short* lo = loB + (size_t)z * DM * DM;

#pragma unroll
    for (int p = 0; p < 2; ++p) {
        int fid = p * 256 + t;
        int kk = fid >> 4, c4 = fid & 15;
        float4 w = *(const float4*)(W + (size_t)(k0 + kk) * DM + n0 + c4 * 4);
        *(float4*)&Wf[kk][c4 * 4] = w;
    }
    __syncthreads();

    const int n = t >> 2, g = t & 3;
    short8v vh, vl;
#pragma unroll
    for (int j = 0; j < 8; ++j) {
        float x = Wf[g * 8 + j][n];
        unsigned short h = bf16_rne(x);
        float hf = __uint_as_float((unsigned int)h << 16);
        unsigned short l = bf16_rne(x - hf);
        vh[j] = (short)h;
        vl[j] = (short)l;
    }
    size_t off = (size_t)(n0 + n) * DM + k0 + g * 8;
    *(short8v*)(hi + off) = vh;
    *(short8v*)(lo + off) = vl;
}

// ---------------------------------------------------------------------------
// Split-bf16 MFMA GEMM: C[M,1024] = A @ B^T + bias, A as hi/lo bf16 [m][k],
// B as hi/lo bf16 [n][k] (pre-transposed W). 128x128 tile, 4 waves (2x2 of
// 64x64), BK=32, 16x16x32 MFMA, 3 products per frag-pair (hh + hl + lh).
// Staging via global_load_lds(16B); XOR swizzle (slot = g ^ ((row>>1)&3))
// applied on the GLOBAL source address (LDS dest linear) and on frag reads —
// same involution both sides (rule 21). k-slot order cancels between A and B.
// ---------------------------------------------------------------------------
__global__ __launch_bounds__(256)
void gemm_split(const unsigned short* __restrict__ Agh,
                const unsigned short* __restrict__ Agl,
                const unsigned short* __restrict__ Bgh,
                const unsigned short* __restrict__ Bgl,
                const float* __restrict__ bias, float* __restrict__ C)
{
    __shared__ __align__(16) unsigned short Ah[128 * 32], Al[128 * 32],
                                            Bh[128 * 32], Bl[128 * 32];
    const int t = threadIdx.x, lane = t & 63, wid = t >> 6;
    const int m0 = blockIdx.x * 128, n0 = blockIdx.y * 128;
    const int wm0 = (wid >> 1) * 64, wn0 = (wid & 1) * 64;
    const int ln = lane & 15, blk = lane >> 4;

    // staging assignment: wave w stages one of the four 8KB buffers
    const unsigned short* gsrc = (wid == 0) ? Agh : (wid == 1) ? Agl
                               : (wid == 2) ? Bgh : Bgl;
    unsigned short* ldst = (wid == 0) ? Ah : (wid == 1) ? Al
                         : (wid == 2) ? Bh : Bl;
    const int r0 = (wid < 2) ? m0 : n0;
    const int lr = lane >> 2, sl = lane & 3;
    const int gg = sl ^ ((lr >> 1) & 3);  // logical k-group this lane fetches
    const unsigned short* gbase = gsrc + (size_t)(r0 + lr) * DM + gg * 8;

    f32x4 zero4 = {0.f, 0.f, 0.f, 0.f};
    f32x4 acc[4][4];
#pragma unroll
    for (int i = 0; i < 4; ++i)
#pragma unroll
        for (int j = 0; j < 4; ++j) acc[i][j] = zero4;

    for (int kt = 0; kt < 1024; kt += 32) {
        __syncthreads();  // protect LDS from previous iteration's reads
#pragma unroll
        for (int i = 0; i < 8; ++i)
            load_lds16(gbase + (size_t)i * 16 * DM + kt, ldst + i * 512);
        __syncthreads();  // drains vmcnt -> staged data visible

        bf16x8 bfh[4], bfl[4];
#pragma unroll
        for (int bn = 0; bn < 4; ++bn) {
            int rn = wn0 + bn * 16 + ln;
            int off = rn * 32 + ((blk ^ ((rn >> 1) & 3)) << 3);
            bfh[bn] = *(const bf16x8*)(Bh + off);
            bfl[bn] = *(const bf16x8*)(Bl + off);
        }
#pragma unroll
        for (int am = 0; am < 4; ++am) {
            int rm = wm0 + am * 16 + ln;
            int off = rm * 32 + ((blk ^ ((rm >> 1) & 3)) << 3);
            bf16x8 afh = *(const bf16x8*)(Ah + off);
            bf16x8 afl = *(const bf16x8*)(Al + off);
#pragma unroll
            for (int bn = 0; bn < 4; ++bn) {
                acc[am][bn] = __builtin_amdgcn_mfma_f32_16x16x32_bf16(
                    afh, bfh[bn], acc[am][bn], 0, 0, 0);
                acc[am][bn] = __builtin_amdgcn_mfma_f32_16x16x32_bf16(
                    afh, bfl[bn], acc[am][bn], 0, 0, 0);
                acc[am][bn] = __builtin_amdgcn_mfma_f32_16x16x32_bf16(
                    afl, bfh[bn], acc[am][bn], 0, 0, 0);
            }
        }
    }

    // epilogue: C/D layout col=lane&15, row=(lane>>4)*4+reg  [measured m89/m91]
#pragma unroll
    for (int bn = 0; bn < 4; ++bn) {
        int col = n0 + wn0 + bn * 16 + ln;
        float bs = bias[col];
#pragma unroll
        for (int am = 0; am < 4; ++am) {
#pragma unroll
            for (int r = 0; r < 4; ++r) {
                int row = m0 + wm0 + am * 16 + blk * 4 + r;
                C[(size_t)row * DM + col] = acc[am][bn][r] + bs;
            }
        }
    }
}

// ---------------------------------------------------------------------------
// Flash-style attention, fp32 (unchanged from round 1).
// ---------------------------------------------------------------------------
__global__ __launch_bounds__(256)
void flash_attn_kernel(const float* __restrict__ Q, const float* __restrict__ K,
                       const float* __restrict__ V, const int* __restrict__ mask,
                       float* __restrict__ OutA)
{
    __shared__ float Qts[64][68];
    __shared__ float KPs[64][68];
    __shared__ float Vs[64][68];
    __shared__ int   msk[64];

    const int t  = threadIdx.x;
    const int tx = t & 15, ty = t >> 4;
    const int q0 = blockIdx.x * 64;
    const int h  = blockIdx.y;
    const int b  = blockIdx.z;

    const float* Qbase = Q + ((size_t)b * SEQ) * DM + (size_t)h * DK;

#pragma unroll
    for (int p = 0; p < 4; ++p) {
        int fid = p * 256 + t;
        int r = fid >> 4, c4 = fid & 15;
        float4 qv = *(const float4*)(Qbase + (size_t)(q0 + r) * DM + c4 * 4);
        Qts[c4 * 4 + 0][r] = qv.x; Qts[c4 * 4 + 1][r] = qv.y;
        Qts[c4 * 4 + 2][r] = qv.z; Qts[c4 * 4 + 3][r] = qv.w;
    }

    float m_i[4], l_i[4], o[4][4];
#pragma unroll
    for (int a = 0; a < 4; ++a) {
        m_i[a] = -INFINITY; l_i[a] = 0.f;
#pragma unroll
        for (int c = 0; c < 4; ++c) o[a][c] = 0.f;
    }

    for (int kt = 0; kt < SEQ; kt += 64) {
        __syncthreads();
        const float* Kbase = K + ((size_t)b * SEQ + kt) * DM + (size_t)h * DK;
        const float* Vbase = V + ((size_t)b * SEQ + kt) * DM + (size_t)h * DK;
#pragma unroll
        for (int p = 0; p < 4; ++p) {
            int fid = p * 256 + t;
            int r = fid >> 4, c4 = fid & 15;
            float4 kv = *(const float4*)(Kbase + (size_t)r * DM + c4 * 4);
            KPs[c4 * 4 + 0][r] = kv.x; KPs[c4 * 4 + 1][r] = kv.y;
            KPs[c4 * 4 + 2][r] = kv.z; KPs[c4 * 4 + 3][r] = kv.w;
            *(float4*)&Vs[r][c4 * 4] =
                *(const float4*)(Vbase + (size_t)r * DM + c4 * 4);
        }
        if (t < 64) msk[t] = mask[(size_t)b * SEQ + kt + t];
        __syncthreads();

        float s[4][4];
#pragma unroll
        for (int a = 0; a < 4; ++a)
#pragma unroll
            for (int c = 0; c < 4; ++c) s[a][c] = 0.f;
#pragma unroll 8
        for (int d = 0; d < 64; ++d) {
            float4 qv = *(float4*)&Qts[d][ty * 4];
            float4 kv = *(float4*)&KPs[d][tx * 4];
            float qa[4] = {qv.x, qv.y, qv.z, qv.w};
            float kb[4] = {kv.x, kv.y, kv.z, kv.w};
#pragma unroll
            for (int a = 0; a < 4; ++a)
#pragma unroll
                for (int c = 0; c < 4; ++c)
                    s[a][c] = fmaf(qa[a], kb[c], s[a][c]);
        }

#pragma unroll
        for (int c = 0; c < 4; ++c) {
            const bool mz = (msk[4 * tx + c] == 0);
#pragma unroll
            for (int a = 0; a < 4; ++a) {
                float e = mz ? -1e20f : s[a][c];
                s[a][c] = e * 0.03125f;
            }
        }

#pragma unroll
        for (int a = 0; a < 4; ++a) {
            float mt = fmaxf(fmaxf(s[a][0], s[a][1]), fmaxf(s[a][2], s[a][3]));
#pragma unroll
            for (int off = 1; off < 16; off <<= 1)
                mt = fmaxf(mt, __shfl_xor(mt, off, 16));
            float mn = fmaxf(m_i[a], mt);
            float al = __expf(m_i[a] - mn);
            m_i[a] = mn;
            float r = 0.f;
#pragma unroll
            for (int c = 0; c < 4; ++c) {
                float p = __expf(s[a][c] - mn);
                s[a][c] = p;
                r += p;
            }
#pragma unroll
            for (int off = 1; off < 16; off <<= 1)
                r += __shfl_xor(r, off, 16);
            l_i[a] = l_i[a] * al + r;
#pragma unroll
            for (int c = 0; c < 4; ++c) o[a][c] *= al;
        }

        __syncthreads();
#pragma unroll
        for (int a = 0; a < 4; ++a) {
            float4 pw = make_float4(s[a][0], s[a][1], s[a][2], s[a][3]);
            *(float4*)&KPs[4 * ty + a][4 * tx] = pw;
        }
        __syncthreads();

#pragma unroll
        for (int j0 = 0; j0 < 64; j0 += 4) {
            float4 pv[4];
#pragma unroll
            for (int a = 0; a < 4; ++a) pv[a] = *(float4*)&KPs[4 * ty + a][j0];
            float4 vv[4];
#pragma unroll
            for (int jj = 0; jj < 4; ++jj)
                vv[jj] = *(float4*)&Vs[j0 + jj][tx * 4];
#pragma unroll
            for (int a = 0; a < 4; ++a) {
                float pa[4] = {pv[a].x, pv[a].y, pv[a].z, pv[a].w};
#pragma unroll
                for (int jj = 0; jj < 4; ++jj) {
                    o[a][0] = fmaf(pa[jj], vv[jj].x, o[a][0]);
                    o[a][1] = fmaf(pa[jj], vv[jj].y, o[a][1]);
                    o[a][2] = fmaf(pa[jj], vv[jj].z, o[a][2]);
                    o[a][3] = fmaf(pa[jj], vv[jj].w, o[a][3]);
                }
            }
        }
    }

#pragma unroll
    for (int a = 0; a < 4; ++a) {
        float inv = 1.f / l_i[a];
        float4 ov = make_float4(o[a][0] * inv, o[a][1] * inv,
                                o[a][2] * inv, o[a][3] * inv);
        *(float4*)(OutA + ((size_t)b * SEQ + q0 + 4 * ty + a) * DM +
                   (size_t)h * DK + 4 * tx) = ov;
    }
}

// ---------------------------------------------------------------------------
extern "C" void kernel_launch(void* const* d_in, const int* in_sizes, int n_in,
                              void* d_out, int out_size, void* d_ws, size_t ws_size,
                              hipStream_t stream)
{
    const float* values = (const float*)d_in[0];
    const float* keys   = (const float*)d_in[1];
    const float* query  = (const float*)d_in[2];
    const int*   mask   = (const int*)d_in[3];
    const float* Wq = (const float*)d_in[4];
    const float* bq = (const float*)d_in[5];
    const float* Wk = (const float*)d_in[6];
    const float* bk = (const float*)d_in[7];
    const float* Wv = (const float*)d_in[8];
    const float* bv = (const float*)d_in[9];
    const float* Wo = (const float*)d_in[10];
    const float* bo = (const float*)d_in[11];
    float* out = (float*)d_out;

    // workspace layout (144 MB total)
    float* Qb = (float*)d_ws;                 // 32 MB
    float* Kb = Qb + NQ;                      // 32 MB
    float* Vb = Kb + NQ;                      // 32 MB
    unsigned short* tAhi = (unsigned short*)(Vb + NQ);   // 16 MB
    unsigned short* tAlo = tAhi + NQ;                    // 16 MB
    unsigned short* Wthi = tAlo + NQ;                    // 8 MB (4 x [n][k])
    unsigned short* Wtlo = Wthi + (size_t)4 * DM * DM;   // 8 MB
    float* Ab = Qb;  // attention output aliases Q buffer (safe: flash kernel
                     // fully stages its Q region in LDS before any write)

    const unsigned short* WqH = Wthi + 0 * (size_t)DM * DM;
    const unsigned short* WkH = Wthi + 1 * (size_t)DM * DM;
    const unsigned short* WvH = Wthi + 2 * (size_t)DM * DM;
    const unsigned short* WoH = Wthi + 3 * (size_t)DM * DM;
    const unsigned short* WqL = Wtlo + 0 * (size_t)DM * DM;
    const unsigned short* WkL = Wtlo + 1 * (size_t)DM * DM;
    const unsigned short* WvL = Wtlo + 2 * (size_t)DM * DM;
    const unsigned short* WoL = Wtlo + 3 * (size_t)DM * DM;

    dim3 blk(256);
    const int convGrid = (int)(NQ / 2048);           // 4096
    const dim3 gemmGrid(MROWS / 128, DM / 128, 1);   // (64, 8)

    // 1. weights -> transposed hi/lo bf16
    conv_w<<<dim3(16, 32, 4), blk, 0, stream>>>(Wq, Wk, Wv, Wo, Wthi, Wtlo);
    // 2-7. projections
    conv_split<<<convGrid, blk, 0, stream>>>(query, tAhi, tAlo);
    gemm_split<<<gemmGrid, blk, 0, stream>>>(tAhi, tAlo, WqH, WqL, bq, Qb);
    conv_split<<<convGrid, blk, 0, stream>>>(keys, tAhi, tAlo);
    gemm_split<<<gemmGrid, blk, 0, stream>>>(tAhi, tAlo, WkH, WkL, bk, Kb);
    conv_split<<<convGrid, blk, 0, stream>>>(values, tAhi, tAlo);
    gemm_split<<<gemmGrid, blk, 0, stream>>>(tAhi, tAlo, WvH, WvL, bv, Vb);
    // 8. attention
    flash_attn_kernel<<<dim3(SEQ / 64, NHEADS, NB), blk, 0, stream>>>(
        Qb, Kb, Vb, mask, Ab);
    // 9-10. output projection
    conv_split<<<convGrid, blk, 0, stream>>>(Ab, tAhi, tAlo);
    gemm_split<<<gemmGrid, blk, 0, stream>>>(tAhi, tAlo, WoH, WoL, bo, out);
}

// Round 5
// 559.213 us; speedup vs baseline: 1.6977x; 1.6977x over previous
//
#include <hip/hip_runtime.h>

// Problem constants
#define DM     1024
#define NHEADS 16
#define DK     64
#define NB     8
#define SEQ    1024
#define MROWS  (NB * SEQ)            // 8192
#define NQ     ((size_t)MROWS * DM)  // 8M elements

typedef unsigned short u16;
typedef __attribute__((ext_vector_type(8))) __bf16 bf16x8;
typedef __attribute__((ext_vector_type(8))) short  short8v;
typedef __attribute__((ext_vector_type(4))) float  f32x4;

typedef const __attribute__((address_space(1))) void* gas_ptr;
typedef __attribute__((address_space(3))) void*       las_ptr;

__device__ __forceinline__ void load_lds16(const void* g, void* l) {
    __builtin_amdgcn_global_load_lds((gas_ptr)g, (las_ptr)l, 16, 0, 0);
}
__device__ __forceinline__ void load_lds4(const void* g, void* l) {
    __builtin_amdgcn_global_load_lds((gas_ptr)g, (las_ptr)l, 4, 0, 0);
}

__device__ __forceinline__ u16 bf16_rne(float x) {
    unsigned int u = __float_as_uint(x);
    u += 0x7FFFu + ((u >> 16) & 1u);
    return (u16)(u >> 16);
}

// ---------------------------------------------------------------------------
// conv_split: fp32 -> bf16 hi + bf16 lo (RNE; lo = rne(x - hi)).
// ---------------------------------------------------------------------------
__global__ __launch_bounds__(256)
void conv_split(const float* __restrict__ in, u16* __restrict__ hi,
                u16* __restrict__ lo)
{
    size_t i8 = ((size_t)blockIdx.x * 256 + threadIdx.x) * 8;
    float4 x0 = *(const float4*)(in + i8);
    float4 x1 = *(const float4*)(in + i8 + 4);
    float xs[8] = {x0.x, x0.y, x0.z, x0.w, x1.x, x1.y, x1.z, x1.w};
    short8v vh, vl;
#pragma unroll
    for (int j = 0; j < 8; ++j) {
        u16 h = bf16_rne(xs[j]);
        float hf = __uint_as_float((unsigned int)h << 16);
        vh[j] = (short)h;
        vl[j] = (short)bf16_rne(xs[j] - hf);
    }
    *(short8v*)(hi + i8) = vh;
    *(short8v*)(lo + i8) = vl;
}

// ---------------------------------------------------------------------------
// conv_w: W [k][n] fp32 -> Wt hi/lo [n][k] bf16 (transposed split), 4 weights.
// ---------------------------------------------------------------------------
__global__ __launch_bounds__(256)
void conv_w(const float* __restrict__ W0, const float* __restrict__ W1,
            const float* __restrict__ W2, const float* __restrict__ W3,
            u16* __restrict__ hiB, u16* __restrict__ loB)
{
    __shared__ float Wf[32][68];
    const int t = threadIdx.x;
    const int n0 = blockIdx.x * 64, k0 = blockIdx.y * 32, z = blockIdx.z;
    const float* W = (z == 0) ? W0 : (z == 1) ? W1 : (z == 2) ? W2 : W3;
    u16* hi = hiB + (size_t)z * DM * DM;
    u16* lo = loB + (size_t)z * DM * DM;

#pragma unroll
    for (int p = 0; p < 2; ++p) {
        int fid = p * 256 + t;
        int kk = fid >> 4, c4 = fid & 15;
        *(float4*)&Wf[kk][c4 * 4] =
            *(const float4*)(W + (size_t)(k0 + kk) * DM + n0 + c4 * 4);
    }
    __syncthreads();

    const int n = t >> 2, g = t & 3;
    short8v vh, vl;
#pragma unroll
    for (int j = 0; j < 8; ++j) {
        float x = Wf[g * 8 + j][n];
        u16 h = bf16_rne(x);
        float hf = __uint_as_float((unsigned int)h << 16);
        vh[j] = (short)h;
        vl[j] = (short)bf16_rne(x - hf);
    }
    size_t off = (size_t)(n0 + n) * DM + k0 + g * 8;
    *(short8v*)(hi + off) = vh;
    *(short8v*)(lo + off) = vl;
}

// ---------------------------------------------------------------------------
// Split-bf16 MFMA GEMM (verified layout, round-4 pass). MODE selects epilogue:
// 0 = fp32 out; 1 = hi/lo bf16 pair; 2 = single bf16.
// ---------------------------------------------------------------------------
template <int MODE>
__global__ __launch_bounds__(256)
void gemm_split_t(const u16* __restrict__ Agh, const u16* __restrict__ Agl,
                  const u16* __restrict__ Bgh, const u16* __restrict__ Bgl,
                  const float* __restrict__ bias, float* __restrict__ Cf,
                  u16* __restrict__ C1, u16* __restrict__ C2)
{
    __shared__ __align__(16) u16 Ah[128 * 32], Al[128 * 32],
                                 Bh[128 * 32], Bl[128 * 32];
    const int t = threadIdx.x, lane = t & 63, wid = t >> 6;
    const int m0 = blockIdx.x * 128, n0 = blockIdx.y * 128;
    const int wm0 = (wid >> 1) * 64, wn0 = (wid & 1) * 64;
    const int ln = lane & 15, blk = lane >> 4;

    const u16* gsrc = (wid == 0) ? Agh : (wid == 1) ? Agl
                    : (wid == 2) ? Bgh : Bgl;
    u16* ldst = (wid == 0) ? Ah : (wid == 1) ? Al : (wid == 2) ? Bh : Bl;
    const int r0 = (wid < 2) ? m0 : n0;
    const int lr = lane >> 2, sl = lane & 3;
    const int gg = sl ^ ((lr >> 1) & 3);
    const u16* gbase = gsrc + (size_t)(r0 + lr) * DM + gg * 8;

    f32x4 zero4 = {0.f, 0.f, 0.f, 0.f};
    f32x4 acc[4][4];
#pragma unroll
    for (int i = 0; i < 4; ++i)
#pragma unroll
        for (int j = 0; j < 4; ++j) acc[i][j] = zero4;

    for (int kt = 0; kt < 1024; kt += 32) {
        __syncthreads();
#pragma unroll
        for (int i = 0; i < 8; ++i)
            load_lds16(gbase + (size_t)i * 16 * DM + kt, ldst + i * 512);
        __syncthreads();

        bf16x8 bfh[4], bfl[4];
#pragma unroll
        for (int bn = 0; bn < 4; ++bn) {
            int rn = wn0 + bn * 16 + ln;
            int off = rn * 32 + ((blk ^ ((rn >> 1) & 3)) << 3);
            bfh[bn] = *(const bf16x8*)(Bh + off);
            bfl[bn] = *(const bf16x8*)(Bl + off);
        }
#pragma unroll
        for (int am = 0; am < 4; ++am) {
            int rm = wm0 + am * 16 + ln;
            int off = rm * 32 + ((blk ^ ((rm >> 1) & 3)) << 3);
            bf16x8 afh = *(const bf16x8*)(Ah + off);
            bf16x8 afl = *(const bf16x8*)(Al + off);
#pragma unroll
            for (int bn = 0; bn < 4; ++bn) {
                acc[am][bn] = __builtin_amdgcn_mfma_f32_16x16x32_bf16(
                    afh, bfh[bn], acc[am][bn], 0, 0, 0);
                acc[am][bn] = __builtin_amdgcn_mfma_f32_16x16x32_bf16(
                    afh, bfl[bn], acc[am][bn], 0, 0, 0);
                acc[am][bn] = __builtin_amdgcn_mfma_f32_16x16x32_bf16(
                    afl, bfh[bn], acc[am][bn], 0, 0, 0);
            }
        }
    }

    // C/D layout: col = lane&15, row = (lane>>4)*4 + reg
#pragma unroll
    for (int bn = 0; bn < 4; ++bn) {
        int col = n0 + wn0 + bn * 16 + ln;
        float bs = bias[col];
#pragma unroll
        for (int am = 0; am < 4; ++am) {
#pragma unroll
            for (int r = 0; r < 4; ++r) {
                int row = m0 + wm0 + am * 16 + blk * 4 + r;
                float v = acc[am][bn][r] + bs;
                size_t idx = (size_t)row * DM + col;
                if (MODE == 0) {
                    Cf[idx] = v;
                } else if (MODE == 1) {
                    u16 h = bf16_rne(v);
                    float hf = __uint_as_float((unsigned int)h << 16);
                    C1[idx] = h;
                    C2[idx] = bf16_rne(v - hf);
                } else {
                    C1[idx] = bf16_rne(v);
                }
            }
        }
    }
}

// ---------------------------------------------------------------------------
// v_transpose: Vbf [b,s,h,d] bf16 -> Vt [b,h,d,s] bf16. 64x64 tiles via LDS.
// ---------------------------------------------------------------------------
__global__ __launch_bounds__(256)
void v_transpose(const u16* __restrict__ Vbf, u16* __restrict__ Vt)
{
    __shared__ u16 Ls[64][66];  // pad 66: 2-way max on scalar access patterns
    const int t = threadIdx.x;
    const int s0 = blockIdx.x * 64, h = blockIdx.y, b = blockIdx.z;
#pragma unroll
    for (int p = 0; p < 2; ++p) {
        int id = p * 256 + t;
        int s = id >> 3, c8 = id & 7;
        short8v v = *(const short8v*)(Vbf + (size_t)(b * SEQ + s0 + s) * DM +
                                      h * DK + c8 * 8);
#pragma unroll
        for (int j = 0; j < 8; ++j) Ls[s][c8 * 8 + j] = (u16)v[j];
    }
    __syncthreads();
#pragma unroll
    for (int p = 0; p < 2; ++p) {
        int id = p * 256 + t;
        int d = id >> 3, s8 = id & 7;
        short8v v;
#pragma unroll
        for (int j = 0; j < 8; ++j) v[j] = (short)Ls[s8 * 8 + j][d];
        *(short8v*)(Vt + (size_t)((b * NHEADS + h) * DK + d) * SEQ + s0 +
                    s8 * 8) = v;
    }
}

// ---------------------------------------------------------------------------
// attn_mfma: flash attention on MFMA. Q,K hi/lo bf16 [b,s,h*d]; Vt bf16
// [b,h,d,s]; out fp32 [b,s,d_model]. 128 q-rows/block, 4 waves x 32 q-rows,
// KV tiles of 64. All LDS tiles stored with 16B-slot XOR swizzle
// (slot' = slot ^ (row&7)) applied on the global source addr (dest linear,
// rule 21) and on fragment reads -> conflict-free ds_read_b128.
// ---------------------------------------------------------------------------
__global__ __launch_bounds__(256)
void attn_mfma(const u16* __restrict__ Qh, const u16* __restrict__ Ql,
               const u16* __restrict__ Kh, const u16* __restrict__ Kl,
               const u16* __restrict__ Vt, const int* __restrict__ mask,
               float* __restrict__ OutA)
{
    __shared__ __align__(16) u16 Qhs[128 * 64], Qls[128 * 64];
    __shared__ __align__(16) u16 Khs[64 * 64], Kls[64 * 64], Vts[64 * 64];
    __shared__ __align__(16) u16 Ps[4][16 * 64];
    __shared__ int msk_s[64];

    const int t = threadIdx.x, lane = t & 63, wid = t >> 6;
    const int q0 = blockIdx.x * 128;
    const int h = blockIdx.y, b = blockIdx.z;
    const int ln = lane & 15, blk = lane >> 4;

    // staging lane constants (row-within-instr, swizzled source chunk)
    const int srow = lane >> 3;
    const int schk = (lane & 7) ^ srow;

    // ---- stage Q tile (128 q x 64 d), hi and lo ----
    {
        const size_t qg =
            (size_t)(b * SEQ + q0 + srow) * DM + h * DK + schk * 8;
        for (int i = wid; i < 16; i += 4) {
            load_lds16(Qh + qg + (size_t)i * 8 * DM, (char*)Qhs + i * 1024);
            load_lds16(Ql + qg + (size_t)i * 8 * DM, (char*)Qls + i * 1024);
        }
    }

    float m_i[2][4], l_i[2][4];
    f32x4 oacc[2][4];
    f32x4 zero4 = {0.f, 0.f, 0.f, 0.f};
#pragma unroll
    for (int am = 0; am < 2; ++am) {
#pragma unroll
        for (int r = 0; r < 4; ++r) { m_i[am][r] = -INFINITY; l_i[am][r] = 0.f; }
#pragma unroll
        for (int bn = 0; bn < 4; ++bn) oacc[am][bn] = zero4;
    }

    for (int kv0 = 0; kv0 < SEQ; kv0 += 64) {
        __syncthreads();  // previous tile's LDS reads complete
        if (wid == 0) {
            const size_t kg =
                (size_t)(b * SEQ + kv0 + srow) * DM + h * DK + schk * 8;
#pragma unroll
            for (int i = 0; i < 8; ++i)
                load_lds16(Kh + kg + (size_t)i * 8 * DM, (char*)Khs + i * 1024);
        } else if (wid == 1) {
            const size_t kg =
                (size_t)(b * SEQ + kv0 + srow) * DM + h * DK + schk * 8;
#pragma unroll
            for (int i = 0; i < 8; ++i)
                load_lds16(Kl + kg + (size_t)i * 8 * DM, (char*)Kls + i * 1024);
        } else if (wid == 2) {
            const size_t vg =
                (size_t)((b * NHEADS + h) * DK + srow) * SEQ + kv0 + schk * 8;
#pragma unroll
            for (int i = 0; i < 8; ++i)
                load_lds16(Vt + vg + (size_t)i * 8 * SEQ, (char*)Vts + i * 1024);
        } else {
            load_lds4(mask + (size_t)b * SEQ + kv0 + lane, (char*)msk_s);
        }
        __syncthreads();  // staged data visible (barrier drains vmcnt)

        int mvals[4];
#pragma unroll
        for (int ct = 0; ct < 4; ++ct) mvals[ct] = msk_s[ct * 16 + ln];

#pragma unroll
        for (int am = 0; am < 2; ++am) {
            // ---- QK^T: S[16 q][64 kv], split hi/lo (hh + hl + lh) ----
            const int qrow = wid * 32 + am * 16 + ln;
            bf16x8 qh[2], ql[2];
#pragma unroll
            for (int ks = 0; ks < 2; ++ks) {
                int idx = qrow * 64 + (((ks * 4 + blk) ^ (qrow & 7)) << 3);
                qh[ks] = *(const bf16x8*)(Qhs + idx);
                ql[ks] = *(const bf16x8*)(Qls + idx);
            }
            f32x4 s[4];
#pragma unroll
            for (int ct = 0; ct < 4; ++ct) s[ct] = zero4;
#pragma unroll
            for (int ct = 0; ct < 4; ++ct) {
                int krow = ct * 16 + ln;
#pragma unroll
                for (int ks = 0; ks < 2; ++ks) {
                    int idx = krow * 64 + (((ks * 4 + blk) ^ (krow & 7)) << 3);
                    bf16x8 kf = *(const bf16x8*)(Khs + idx);
                    bf16x8 kg2 = *(const bf16x8*)(Kls + idx);
                    s[ct] = __builtin_amdgcn_mfma_f32_16x16x32_bf16(
                        qh[ks], kf, s[ct], 0, 0, 0);
                    s[ct] = __builtin_amdgcn_mfma_f32_16x16x32_bf16(
                        qh[ks], kg2, s[ct], 0, 0, 0);
                    s[ct] = __builtin_amdgcn_mfma_f32_16x16x32_bf16(
                        ql[ks], kf, s[ct], 0, 0, 0);
                }
            }
            // mask (ref order: mask, then scale by 1/32)
#pragma unroll
            for (int ct = 0; ct < 4; ++ct) {
                const bool mz = (mvals[ct] == 0);
#pragma unroll
                for (int r = 0; r < 4; ++r) {
                    float e = mz ? -1e20f : s[ct][r];
                    s[ct][r] = e * 0.03125f;
                }
            }
            // online softmax: lane's rows are q = blk*4 + r; row spread
            // across the 16 ln-lanes (4 ct regs each)
#pragma unroll
            for (int r = 0; r < 4; ++r) {
                float mt = fmaxf(fmaxf(s[0][r], s[1][r]),
                                 fmaxf(s[2][r], s[3][r]));
#pragma unroll
                for (int off = 1; off < 16; off <<= 1)
                    mt = fmaxf(mt, __shfl_xor(mt, off, 16));
                float mn = fmaxf(m_i[am][r], mt);
                float al = __expf(m_i[am][r] - mn);
                m_i[am][r] = mn;
                float rs = 0.f;
#pragma unroll
                for (int ct = 0; ct < 4; ++ct) {
                    float p = __expf(s[ct][r] - mn);
                    s[ct][r] = p;
                    rs += p;
                }
#pragma unroll
                for (int off = 1; off < 16; off <<= 1)
                    rs += __shfl_xor(rs, off, 16);
                l_i[am][r] = l_i[am][r] * al + rs;
#pragma unroll
                for (int bn = 0; bn < 4; ++bn) oacc[am][bn][r] *= al;
            }
            // ---- P -> bf16 -> wave-private LDS (swizzled slots) ----
            u16* P = &Ps[wid][0];
#pragma unroll
            for (int ct = 0; ct < 4; ++ct) {
                int slot = ct * 2 + (ln >> 3);
#pragma unroll
                for (int r = 0; r < 4; ++r) {
                    int q = blk * 4 + r;
                    P[q * 64 + ((slot ^ (q & 7)) << 3) + (ln & 7)] =
                        bf16_rne(s[ct][r]);
                }
            }
            // ---- PV: O[16 q][64 d] += P @ Vt ----
#pragma unroll
            for (int ks = 0; ks < 2; ++ks) {
                int pidx = ln * 64 + (((ks * 4 + blk) ^ (ln & 7)) << 3);
                bf16x8 pa = *(const bf16x8*)(P + pidx);
#pragma unroll
                for (int bn = 0; bn < 4; ++bn) {
                    int vrow = bn * 16 + ln;
                    int vidx =
                        vrow * 64 + (((ks * 4 + blk) ^ (vrow & 7)) << 3);
                    bf16x8 vb = *(const bf16x8*)(Vts + vidx);
                    oacc[am][bn] = __builtin_amdgcn_mfma_f32_16x16x32_bf16(
                        pa, vb, oacc[am][bn], 0, 0, 0);
                }
            }
        }
    }

    // epilogue: normalize, write fp32 concat-head layout
#pragma unroll
    for (int am = 0; am < 2; ++am) {
#pragma unroll
        for (int r = 0; r < 4; ++r) {
            int q = q0 + wid * 32 + am * 16 + blk * 4 + r;
            float inv = 1.f / l_i[am][r];
#pragma unroll
            for (int bn = 0; bn < 4; ++bn) {
                OutA[(size_t)(b * SEQ + q) * DM + h * DK + bn * 16 + ln] =
                    oacc[am][bn][r] * inv;
            }
        }
    }
}

// ---------------------------------------------------------------------------
extern "C" void kernel_launch(void* const* d_in, const int* in_sizes, int n_in,
                              void* d_out, int out_size, void* d_ws, size_t ws_size,
                              hipStream_t stream)
{
    const float* values = (const float*)d_in[0];
    const float* keys   = (const float*)d_in[1];
    const float* query  = (const float*)d_in[2];
    const int*   mask   = (const int*)d_in[3];
    const float* Wq = (const float*)d_in[4];
    const float* bq = (const float*)d_in[5];
    const float* Wk = (const float*)d_in[6];
    const float* bk = (const float*)d_in[7];
    const float* Wv = (const float*)d_in[8];
    const float* bv = (const float*)d_in[9];
    const float* Wo = (const float*)d_in[10];
    const float* bo = (const float*)d_in[11];
    float* out = (float*)d_out;

    // workspace layout: 144 MB total (u16 units)
    u16* Qh   = (u16*)d_ws;
    u16* Ql   = Qh + NQ;
    u16* Kh   = Ql + NQ;
    u16* Kl   = Kh + NQ;
    u16* Vbf  = Kl + NQ;
    u16* Vtb  = Vbf + NQ;
    u16* Wthi = Vtb + NQ;                    // 4 x [n][k], 8 MB
    u16* Wtlo = Wthi + (size_t)4 * DM * DM;  // 8 MB
    u16* tAhi = Wtlo + (size_t)4 * DM * DM;  // 16 MB
    u16* tAlo = tAhi + NQ;                   // 16 MB
    // aliases (temporally disjoint):
    float* Ao = (float*)tAhi;  // attn out (32 MB) over dead tA region
    u16* AoHi = Vbf;           // post-attn split over dead Vbf/Vt
    u16* AoLo = Vtb;

    const u16* WqH = Wthi + 0 * (size_t)DM * DM;
    const u16* WkH = Wthi + 1 * (size_t)DM * DM;
    const u16* WvH = Wthi + 2 * (size_t)DM * DM;
    const u16* WoH = Wthi + 3 * (size_t)DM * DM;
    const u16* WqL = Wtlo + 0 * (size_t)DM * DM;
    const u16* WkL = Wtlo + 1 * (size_t)DM * DM;
    const u16* WvL = Wtlo + 2 * (size_t)DM * DM;
    const u16* WoL = Wtlo + 3 * (size_t)DM * DM;

    dim3 blk(256);
    const int convGrid = (int)(NQ / 2048);
    const dim3 gemmGrid(MROWS / 128, DM / 128, 1);

    conv_w<<<dim3(16, 32, 4), blk, 0, stream>>>(Wq, Wk, Wv, Wo, Wthi, Wtlo);

    conv_split<<<convGrid, blk, 0, stream>>>(query, tAhi, tAlo);
    gemm_split_t<1><<<gemmGrid, blk, 0, stream>>>(tAhi, tAlo, WqH, WqL, bq,
                                                  nullptr, Qh, Ql);
    conv_split<<<convGrid, blk, 0, stream>>>(keys, tAhi, tAlo);
    gemm_split_t<1><<<gemmGrid, blk, 0, stream>>>(tAhi, tAlo, WkH, WkL, bk,
                                                  nullptr, Kh, Kl);
    conv_split<<<convGrid, blk, 0, stream>>>(values, tAhi, tAlo);
    gemm_split_t<2><<<gemmGrid, blk, 0, stream>>>(tAhi, tAlo, WvH, WvL, bv,
                                                  nullptr, Vbf, nullptr);
    v_transpose<<<dim3(16, NHEADS, NB), blk, 0, stream>>>(Vbf, Vtb);

    attn_mfma<<<dim3(SEQ / 128, NHEADS, NB), blk, 0, stream>>>(
        Qh, Ql, Kh, Kl, Vtb, mask, Ao);

    conv_split<<<convGrid, blk, 0, stream>>>(Ao, AoHi, AoLo);
    gemm_split_t<0><<<gemmGrid, blk, 0, stream>>>(AoHi, AoLo, WoH, WoL, bo,
                                                  out, nullptr, nullptr);
}

// Round 6
// 556.242 us; speedup vs baseline: 1.7068x; 1.0053x over previous
//
#include <hip/hip_runtime.h>

// Problem constants
#define DM     1024
#define NHEADS 16
#define DK     64
#define NB     8
#define SEQ    1024
#define MROWS  (NB * SEQ)            // 8192
#define NQ     ((size_t)MROWS * DM)  // 8M elements

typedef unsigned short u16;
typedef __attribute__((ext_vector_type(8))) __bf16 bf16x8;
typedef __attribute__((ext_vector_type(8))) short  short8v;
typedef __attribute__((ext_vector_type(4))) float  f32x4;

typedef const __attribute__((address_space(1))) void* gas_ptr;
typedef __attribute__((address_space(3))) void*       las_ptr;

__device__ __forceinline__ void load_lds16(const void* g, void* l) {
    __builtin_amdgcn_global_load_lds((gas_ptr)g, (las_ptr)l, 16, 0, 0);
}
__device__ __forceinline__ void load_lds4(const void* g, void* l) {
    __builtin_amdgcn_global_load_lds((gas_ptr)g, (las_ptr)l, 4, 0, 0);
}

__device__ __forceinline__ u16 bf16_rne(float x) {
    unsigned int u = __float_as_uint(x);
    u += 0x7FFFu + ((u >> 16) & 1u);
    return (u16)(u >> 16);
}

__device__ __forceinline__ void split_store8(const float* __restrict__ in,
                                             u16* __restrict__ hi,
                                             u16* __restrict__ lo, size_t i8)
{
    float4 x0 = *(const float4*)(in + i8);
    float4 x1 = *(const float4*)(in + i8 + 4);
    float xs[8] = {x0.x, x0.y, x0.z, x0.w, x1.x, x1.y, x1.z, x1.w};
    short8v vh, vl;
#pragma unroll
    for (int j = 0; j < 8; ++j) {
        u16 h = bf16_rne(xs[j]);
        float hf = __uint_as_float((unsigned int)h << 16);
        vh[j] = (short)h;
        vl[j] = (short)bf16_rne(xs[j] - hf);
    }
    *(short8v*)(hi + i8) = vh;
    *(short8v*)(lo + i8) = vl;
}

// ---------------------------------------------------------------------------
// conv_split: fp32 -> bf16 hi + lo. conv_qkv: fused 3-input variant.
// ---------------------------------------------------------------------------
__global__ __launch_bounds__(256)
void conv_split(const float* __restrict__ in, u16* __restrict__ hi,
                u16* __restrict__ lo)
{
    size_t i8 = ((size_t)blockIdx.x * 256 + threadIdx.x) * 8;
    split_store8(in, hi, lo, i8);
}

__global__ __launch_bounds__(256)
void conv_qkv(const float* __restrict__ q, const float* __restrict__ k,
              const float* __restrict__ v, u16* __restrict__ qh,
              u16* __restrict__ ql, u16* __restrict__ kh, u16* __restrict__ kl,
              u16* __restrict__ vh, u16* __restrict__ vl)
{
    const int z = blockIdx.z;
    const float* in = (z == 0) ? q : (z == 1) ? k : v;
    u16* hi = (z == 0) ? qh : (z == 1) ? kh : vh;
    u16* lo = (z == 0) ? ql : (z == 1) ? kl : vl;
    size_t i8 = ((size_t)blockIdx.x * 256 + threadIdx.x) * 8;
    split_store8(in, hi, lo, i8);
}

// ---------------------------------------------------------------------------
// conv_w: W [k][n] fp32 -> Wt hi/lo [n][k] bf16 (transposed split), 4 weights.
// ---------------------------------------------------------------------------
__global__ __launch_bounds__(256)
void conv_w(const float* __restrict__ W0, const float* __restrict__ W1,
            const float* __restrict__ W2, const float* __restrict__ W3,
            u16* __restrict__ hiB, u16* __restrict__ loB)
{
    __shared__ float Wf[32][68];
    const int t = threadIdx.x;
    const int n0 = blockIdx.x * 64, k0 = blockIdx.y * 32, z = blockIdx.z;
    const float* W = (z == 0) ? W0 : (z == 1) ? W1 : (z == 2) ? W2 : W3;
    u16* hi = hiB + (size_t)z * DM * DM;
    u16* lo = loB + (size_t)z * DM * DM;

#pragma unroll
    for (int p = 0; p < 2; ++p) {
        int fid = p * 256 + t;
        int kk = fid >> 4, c4 = fid & 15;
        *(float4*)&Wf[kk][c4 * 4] =
            *(const float4*)(W + (size_t)(k0 + kk) * DM + n0 + c4 * 4);
    }
    __syncthreads();

    const int n = t >> 2, g = t & 3;
    short8v vh, vl;
#pragma unroll
    for (int j = 0; j < 8; ++j) {
        float x = Wf[g * 8 + j][n];
        u16 h = bf16_rne(x);
        float hf = __uint_as_float((unsigned int)h << 16);
        vh[j] = (short)h;
        vl[j] = (short)bf16_rne(x - hf);
    }
    size_t off = (size_t)(n0 + n) * DM + k0 + g * 8;
    *(short8v*)(hi + off) = vh;
    *(short8v*)(lo + off) = vl;
}

// ---------------------------------------------------------------------------
// Split-bf16 MFMA GEMM body (verified layout, round-4/5 pass). mode:
// 0 = fp32 out; 1 = hi/lo bf16 pair; 2 = single bf16.
// ---------------------------------------------------------------------------
__device__ __forceinline__ void gemm_body(
    const u16* __restrict__ Agh, const u16* __restrict__ Agl,
    const u16* __restrict__ Bgh, const u16* __restrict__ Bgl,
    const float* __restrict__ bias, int mode, float* __restrict__ Cf,
    u16* __restrict__ C1, u16* __restrict__ C2)
{
    __shared__ __align__(16) u16 Ah[128 * 32], Al[128 * 32],
                                 Bh[128 * 32], Bl[128 * 32];
    const int t = threadIdx.x, lane = t & 63, wid = t >> 6;
    const int m0 = blockIdx.x * 128, n0 = blockIdx.y * 128;
    const int wm0 = (wid >> 1) * 64, wn0 = (wid & 1) * 64;
    const int ln = lane & 15, blk = lane >> 4;

    const u16* gsrc = (wid == 0) ? Agh : (wid == 1) ? Agl
                    : (wid == 2) ? Bgh : Bgl;
    u16* ldst = (wid == 0) ? Ah : (wid == 1) ? Al : (wid == 2) ? Bh : Bl;
    const int r0 = (wid < 2) ? m0 : n0;
    const int lr = lane >> 2, sl = lane & 3;
    const int gg = sl ^ ((lr >> 1) & 3);
    const u16* gbase = gsrc + (size_t)(r0 + lr) * DM + gg * 8;

    f32x4 zero4 = {0.f, 0.f, 0.f, 0.f};
    f32x4 acc[4][4];
#pragma unroll
    for (int i = 0; i < 4; ++i)
#pragma unroll
        for (int j = 0; j < 4; ++j) acc[i][j] = zero4;

    for (int kt = 0; kt < 1024; kt += 32) {
        __syncthreads();
#pragma unroll
        for (int i = 0; i < 8; ++i)
            load_lds16(gbase + (size_t)i * 16 * DM + kt, ldst + i * 512);
        __syncthreads();

        bf16x8 bfh[4], bfl[4];
#pragma unroll
        for (int bn = 0; bn < 4; ++bn) {
            int rn = wn0 + bn * 16 + ln;
            int off = rn * 32 + ((blk ^ ((rn >> 1) & 3)) << 3);
            bfh[bn] = *(const bf16x8*)(Bh + off);
            bfl[bn] = *(const bf16x8*)(Bl + off);
        }
#pragma unroll
        for (int am = 0; am < 4; ++am) {
            int rm = wm0 + am * 16 + ln;
            int off = rm * 32 + ((blk ^ ((rm >> 1) & 3)) << 3);
            bf16x8 afh = *(const bf16x8*)(Ah + off);
            bf16x8 afl = *(const bf16x8*)(Al + off);
#pragma unroll
            for (int bn = 0; bn < 4; ++bn) {
                acc[am][bn] = __builtin_amdgcn_mfma_f32_16x16x32_bf16(
                    afh, bfh[bn], acc[am][bn], 0, 0, 0);
                acc[am][bn] = __builtin_amdgcn_mfma_f32_16x16x32_bf16(
                    afh, bfl[bn], acc[am][bn], 0, 0, 0);
                acc[am][bn] = __builtin_amdgcn_mfma_f32_16x16x32_bf16(
                    afl, bfh[bn], acc[am][bn], 0, 0, 0);
            }
        }
    }

    // C/D layout: col = lane&15, row = (lane>>4)*4 + reg
#pragma unroll
    for (int bn = 0; bn < 4; ++bn) {
        int col = n0 + wn0 + bn * 16 + ln;
        float bs = bias[col];
#pragma unroll
        for (int am = 0; am < 4; ++am) {
#pragma unroll
            for (int r = 0; r < 4; ++r) {
                int row = m0 + wm0 + am * 16 + blk * 4 + r;
                float v = acc[am][bn][r] + bs;
                size_t idx = (size_t)row * DM + col;
                if (mode == 0) {
                    Cf[idx] = v;
                } else if (mode == 1) {
                    u16 h = bf16_rne(v);
                    float hf = __uint_as_float((unsigned int)h << 16);
                    C1[idx] = h;
                    C2[idx] = bf16_rne(v - hf);
                } else {
                    C1[idx] = bf16_rne(v);
                }
            }
        }
    }
}

__global__ __launch_bounds__(256)
void gemm_one(const u16* __restrict__ Agh, const u16* __restrict__ Agl,
              const u16* __restrict__ Bgh, const u16* __restrict__ Bgl,
              const float* __restrict__ bias, int mode, float* __restrict__ Cf,
              u16* __restrict__ C1, u16* __restrict__ C2)
{
    gemm_body(Agh, Agl, Bgh, Bgl, bias, mode, Cf, C1, C2);
}

__global__ __launch_bounds__(256)
void gemm_qkv(const u16* __restrict__ Aqh, const u16* __restrict__ Aql,
              const u16* __restrict__ Akh, const u16* __restrict__ Akl,
              const u16* __restrict__ Avh, const u16* __restrict__ Avl,
              const u16* __restrict__ Wqh, const u16* __restrict__ Wql,
              const u16* __restrict__ Wkh, const u16* __restrict__ Wkl,
              const u16* __restrict__ Wvh, const u16* __restrict__ Wvl,
              const float* __restrict__ bq, const float* __restrict__ bk,
              const float* __restrict__ bv, u16* __restrict__ Qh,
              u16* __restrict__ Ql, u16* __restrict__ Kh, u16* __restrict__ Kl,
              u16* __restrict__ Vbf)
{
    const int z = blockIdx.z;
    const u16* Ah = (z == 0) ? Aqh : (z == 1) ? Akh : Avh;
    const u16* Al = (z == 0) ? Aql : (z == 1) ? Akl : Avl;
    const u16* Bh = (z == 0) ? Wqh : (z == 1) ? Wkh : Wvh;
    const u16* Bl = (z == 0) ? Wql : (z == 1) ? Wkl : Wvl;
    const float* bias = (z == 0) ? bq : (z == 1) ? bk : bv;
    u16* C1 = (z == 0) ? Qh : (z == 1) ? Kh : Vbf;
    u16* C2 = (z == 0) ? Ql : (z == 1) ? Kl : nullptr;
    gemm_body(Ah, Al, Bh, Bl, bias, (z == 2) ? 2 : 1, nullptr, C1, C2);
}

// ---------------------------------------------------------------------------
// v_transpose: Vbf [b,s,h,d] bf16 -> Vt [b,h,d,s] bf16. 64x64 tiles via LDS.
// ---------------------------------------------------------------------------
__global__ __launch_bounds__(256)
void v_transpose(const u16* __restrict__ Vbf, u16* __restrict__ Vt)
{
    __shared__ u16 Ls[64][66];
    const int t = threadIdx.x;
    const int s0 = blockIdx.x * 64, h = blockIdx.y, b = blockIdx.z;
#pragma unroll
    for (int p = 0; p < 2; ++p) {
        int id = p * 256 + t;
        int s = id >> 3, c8 = id & 7;
        short8v v = *(const short8v*)(Vbf + (size_t)(b * SEQ + s0 + s) * DM +
                                      h * DK + c8 * 8);
#pragma unroll
        for (int j = 0; j < 8; ++j) Ls[s][c8 * 8 + j] = (u16)v[j];
    }
    __syncthreads();
#pragma unroll
    for (int p = 0; p < 2; ++p) {
        int id = p * 256 + t;
        int d = id >> 3, s8 = id & 7;
        short8v v;
#pragma unroll
        for (int j = 0; j < 8; ++j) v[j] = (short)Ls[s8 * 8 + j][d];
        *(short8v*)(Vt + (size_t)((b * NHEADS + h) * DK + d) * SEQ + s0 +
                    s8 * 8) = v;
    }
}

// ---------------------------------------------------------------------------
// attn_mfma: flash attention on MFMA. Q in REGISTERS (hoisted, no Q-LDS);
// K hi/lo + Vt staged in LDS (swizzled); defer-max online softmax with the
// 1/32 scale folded into the exp's fmaf; epilogue emits hi/lo bf16 directly.
// 128 q-rows/block, 4 waves x 32 q, KV tiles of 64. LDS ~33 KB.
// ---------------------------------------------------------------------------
__global__ __launch_bounds__(256)
void attn_mfma(const u16* __restrict__ Qh, const u16* __restrict__ Ql,
               const u16* __restrict__ Kh, const u16* __restrict__ Kl,
               const u16* __restrict__ Vt, const int* __restrict__ mask,
               u16* __restrict__ AoHi, u16* __restrict__ AoLo)
{
    __shared__ __align__(16) u16 Khs[64 * 64], Kls[64 * 64], Vts[64 * 64];
    __shared__ __align__(16) u16 Ps[4][16 * 64];
    __shared__ int msk_s[64];

    const int t = threadIdx.x, lane = t & 63, wid = t >> 6;
    const int q0 = blockIdx.x * 128;
    const int h = blockIdx.y, b = blockIdx.z;
    const int ln = lane & 15, blk = lane >> 4;
    const int srow = lane >> 3;
    const int schk = (lane & 7) ^ srow;

    // ---- Q fragments straight to registers (one-time) ----
    bf16x8 qfh[2][2], qfl[2][2];
#pragma unroll
    for (int am = 0; am < 2; ++am) {
        int row = q0 + wid * 32 + am * 16 + ln;
        size_t base = (size_t)(b * SEQ + row) * DM + h * DK;
#pragma unroll
        for (int ks = 0; ks < 2; ++ks) {
            qfh[am][ks] = *(const bf16x8*)(Qh + base + (ks * 4 + blk) * 8);
            qfl[am][ks] = *(const bf16x8*)(Ql + base + (ks * 4 + blk) * 8);
        }
    }

    float m_i[2][4], l_i[2][4];
    f32x4 oacc[2][4];
    f32x4 zero4 = {0.f, 0.f, 0.f, 0.f};
#pragma unroll
    for (int am = 0; am < 2; ++am) {
#pragma unroll
        for (int r = 0; r < 4; ++r) { m_i[am][r] = -INFINITY; l_i[am][r] = 0.f; }
#pragma unroll
        for (int bn = 0; bn < 4; ++bn) oacc[am][bn] = zero4;
    }

    for (int kv0 = 0; kv0 < SEQ; kv0 += 64) {
        __syncthreads();
        if (wid == 0) {
            const size_t kg =
                (size_t)(b * SEQ + kv0 + srow) * DM + h * DK + schk * 8;
#pragma unroll
            for (int i = 0; i < 8; ++i)
                load_lds16(Kh + kg + (size_t)i * 8 * DM, (char*)Khs + i * 1024);
        } else if (wid == 1) {
            const size_t kg =
                (size_t)(b * SEQ + kv0 + srow) * DM + h * DK + schk * 8;
#pragma unroll
            for (int i = 0; i < 8; ++i)
                load_lds16(Kl + kg + (size_t)i * 8 * DM, (char*)Kls + i * 1024);
        } else if (wid == 2) {
            const size_t vg =
                (size_t)((b * NHEADS + h) * DK + srow) * SEQ + kv0 + schk * 8;
#pragma unroll
            for (int i = 0; i < 8; ++i)
                load_lds16(Vt + vg + (size_t)i * 8 * SEQ, (char*)Vts + i * 1024);
        } else {
            load_lds4(mask + (size_t)b * SEQ + kv0 + lane, (char*)msk_s);
        }
        __syncthreads();

        int mvals[4];
#pragma unroll
        for (int ct = 0; ct < 4; ++ct) mvals[ct] = msk_s[ct * 16 + ln];

#pragma unroll
        for (int am = 0; am < 2; ++am) {
            // ---- QK^T (split hi/lo: hh + hl + lh) ----
            f32x4 s[4];
#pragma unroll
            for (int ct = 0; ct < 4; ++ct) s[ct] = zero4;
#pragma unroll
            for (int ct = 0; ct < 4; ++ct) {
                int krow = ct * 16 + ln;
#pragma unroll
                for (int ks = 0; ks < 2; ++ks) {
                    int idx = krow * 64 + (((ks * 4 + blk) ^ (krow & 7)) << 3);
                    bf16x8 kf = *(const bf16x8*)(Khs + idx);
                    bf16x8 kg2 = *(const bf16x8*)(Kls + idx);
                    s[ct] = __builtin_amdgcn_mfma_f32_16x16x32_bf16(
                        qfh[am][ks], kf, s[ct], 0, 0, 0);
                    s[ct] = __builtin_amdgcn_mfma_f32_16x16x32_bf16(
                        qfh[am][ks], kg2, s[ct], 0, 0, 0);
                    s[ct] = __builtin_amdgcn_mfma_f32_16x16x32_bf16(
                        qfl[am][ks], kf, s[ct], 0, 0, 0);
                }
            }
            // mask on raw scores (scale folded into exp below)
#pragma unroll
            for (int ct = 0; ct < 4; ++ct) {
                if (mvals[ct] == 0) {
#pragma unroll
                    for (int r = 0; r < 4; ++r) s[ct][r] = -1e20f;
                }
            }
            // online softmax: defer-max (THR=8 in scaled space)
#pragma unroll
            for (int r = 0; r < 4; ++r) {
                float mt = fmaxf(fmaxf(s[0][r], s[1][r]),
                                 fmaxf(s[2][r], s[3][r]));
#pragma unroll
                for (int off = 1; off < 16; off <<= 1)
                    mt = fmaxf(mt, __shfl_xor(mt, off, 16));
                float pmax = mt * 0.03125f;
                if (pmax > m_i[am][r] + 8.f) {
                    float al = __expf(m_i[am][r] - pmax);
                    m_i[am][r] = pmax;
                    l_i[am][r] *= al;
#pragma unroll
                    for (int bn = 0; bn < 4; ++bn) oacc[am][bn][r] *= al;
                }
                float mn = m_i[am][r];
                float rs = 0.f;
#pragma unroll
                for (int ct = 0; ct < 4; ++ct) {
                    float p = __expf(fmaf(s[ct][r], 0.03125f, -mn));
                    s[ct][r] = p;
                    rs += p;
                }
#pragma unroll
                for (int off = 1; off < 16; off <<= 1)
                    rs += __shfl_xor(rs, off, 16);
                l_i[am][r] += rs;
            }
            // ---- P -> bf16 -> wave-private LDS (swizzled slots) ----
            u16* P = &Ps[wid][0];
#pragma unroll
            for (int ct = 0; ct < 4; ++ct) {
                int slot = ct * 2 + (ln >> 3);
#pragma unroll
                for (int r = 0; r < 4; ++r) {
                    int q = blk * 4 + r;
                    P[q * 64 + ((slot ^ (q & 7)) << 3) + (ln & 7)] =
                        bf16_rne(s[ct][r]);
                }
            }
            // ---- PV: O[16 q][64 d] += P @ Vt ----
#pragma unroll
            for (int ks = 0; ks < 2; ++ks) {
                int pidx = ln * 64 + (((ks * 4 + blk) ^ (ln & 7)) << 3);
                bf16x8 pa = *(const bf16x8*)(P + pidx);
#pragma unroll
                for (int bn = 0; bn < 4; ++bn) {
                    int vrow = bn * 16 + ln;
                    int vidx =
                        vrow * 64 + (((ks * 4 + blk) ^ (vrow & 7)) << 3);
                    bf16x8 vb = *(const bf16x8*)(Vts + vidx);
                    oacc[am][bn] = __builtin_amdgcn_mfma_f32_16x16x32_bf16(
                        pa, vb, oacc[am][bn], 0, 0, 0);
                }
            }
        }
    }

    // epilogue: normalize, split to hi/lo bf16, concat-head layout
#pragma unroll
    for (int am = 0; am < 2; ++am) {
#pragma unroll
        for (int r = 0; r < 4; ++r) {
            int q = q0 + wid * 32 + am * 16 + blk * 4 + r;
            float inv = 1.f / l_i[am][r];
            size_t rowbase = (size_t)(b * SEQ + q) * DM + h * DK;
#pragma unroll
            for (int bn = 0; bn < 4; ++bn) {
                float v = oacc[am][bn][r] * inv;
                u16 uh = bf16_rne(v);
                float hf = __uint_as_float((unsigned int)uh << 16);
                size_t idx = rowbase + bn * 16 + ln;
                AoHi[idx] = uh;
                AoLo[idx] = bf16_rne(v - hf);
            }
        }
    }
}

// ---------------------------------------------------------------------------
extern "C" void kernel_launch(void* const* d_in, const int* in_sizes, int n_in,
                              void* d_out, int out_size, void* d_ws, size_t ws_size,
                              hipStream_t stream)
{
    const float* values = (const float*)d_in[0];
    const float* keys   = (const float*)d_in[1];
    const float* query  = (const float*)d_in[2];
    const int*   mask   = (const int*)d_in[3];
    const float* Wq = (const float*)d_in[4];
    const float* bq = (const float*)d_in[5];
    const float* Wk = (const float*)d_in[6];
    const float* bk = (const float*)d_in[7];
    const float* Wv = (const float*)d_in[8];
    const float* bv = (const float*)d_in[9];
    const float* Wo = (const float*)d_in[10];
    const float* bo = (const float*)d_in[11];
    float* out = (float*)d_out;

    dim3 blk(256);
    const int convGrid = (int)(NQ / 2048);
    const dim3 gemmGrid(MROWS / 128, DM / 128, 1);
    const dim3 gemmGrid3(MROWS / 128, DM / 128, 3);

    const bool fused = ws_size >= (size_t)12 * NQ * 2;  // 192 MB

    if (fused) {
        // layout (u16 units): Qh Ql Kh Kl | Vbf | Wthi Wtlo | tA q/k/v hi+lo
        u16* Qh   = (u16*)d_ws;
        u16* Ql   = Qh + NQ;
        u16* Kh   = Ql + NQ;
        u16* Kl   = Kh + NQ;
        u16* Vbf  = Kl + NQ;
        u16* Wthi = Vbf + NQ;
        u16* Wtlo = Wthi + (size_t)4 * DM * DM;
        u16* tAqh = Wtlo + (size_t)4 * DM * DM;
        u16* tAql = tAqh + NQ;
        u16* tAkh = tAql + NQ;
        u16* tAkl = tAkh + NQ;
        u16* tAvh = tAkl + NQ;
        u16* tAvl = tAvh + NQ;
        u16* Vtb  = tAqh;  // alias: tA dead after gemm_qkv
        u16* AoHi = tAkh;  // alias: dead after gemm_qkv
        u16* AoLo = tAkl;

        const u16* WqH = Wthi + 0 * (size_t)DM * DM;
        const u16* WkH = Wthi + 1 * (size_t)DM * DM;
        const u16* WvH = Wthi + 2 * (size_t)DM * DM;
        const u16* WoH = Wthi + 3 * (size_t)DM * DM;
        const u16* WqL = Wtlo + 0 * (size_t)DM * DM;
        const u16* WkL = Wtlo + 1 * (size_t)DM * DM;
        const u16* WvL = Wtlo + 2 * (size_t)DM * DM;
        const u16* WoL = Wtlo + 3 * (size_t)DM * DM;

        conv_w<<<dim3(16, 32, 4), blk, 0, stream>>>(Wq, Wk, Wv, Wo, Wthi, Wtlo);
        conv_qkv<<<dim3(convGrid, 1, 3), blk, 0, stream>>>(
            query, keys, values, tAqh, tAql, tAkh, tAkl, tAvh, tAvl);
        gemm_qkv<<<gemmGrid3, blk, 0, stream>>>(
            tAqh, tAql, tAkh, tAkl, tAvh, tAvl, WqH, WqL, WkH, WkL, WvH, WvL,
            bq, bk, bv, Qh, Ql, Kh, Kl, Vbf);
        v_transpose<<<dim3(16, NHEADS, NB), blk, 0, stream>>>(Vbf, Vtb);
        attn_mfma<<<dim3(SEQ / 128, NHEADS, NB), blk, 0, stream>>>(
            Qh, Ql, Kh, Kl, Vtb, mask, AoHi, AoLo);
        gemm_one<<<gemmGrid, blk, 0, stream>>>(AoHi, AoLo, WoH, WoL, bo, 0,
                                               out, nullptr, nullptr);
    } else {
        // 144 MB serialized layout (round-5 style, minus the 4th conv pass)
        u16* Qh   = (u16*)d_ws;
        u16* Ql   = Qh + NQ;
        u16* Kh   = Ql + NQ;
        u16* Kl   = Kh + NQ;
        u16* Vbf  = Kl + NQ;
        u16* Vtb  = Vbf + NQ;
        u16* Wthi = Vtb + NQ;
        u16* Wtlo = Wthi + (size_t)4 * DM * DM;
        u16* tAhi = Wtlo + (size_t)4 * DM * DM;
        u16* tAlo = tAhi + NQ;
        u16* AoHi = tAhi;  // alias: tA dead after V-gemm
        u16* AoLo = tAlo;

        const u16* WqH = Wthi + 0 * (size_t)DM * DM;
        const u16* WkH = Wthi + 1 * (size_t)DM * DM;
        const u16* WvH = Wthi + 2 * (size_t)DM * DM;
        const u16* WoH = Wthi + 3 * (size_t)DM * DM;
        const u16* WqL = Wtlo + 0 * (size_t)DM * DM;
        const u16* WkL = Wtlo + 1 * (size_t)DM * DM;
        const u16* WvL = Wtlo + 2 * (size_t)DM * DM;
        const u16* WoL = Wtlo + 3 * (size_t)DM * DM;

        conv_w<<<dim3(16, 32, 4), blk, 0, stream>>>(Wq, Wk, Wv, Wo, Wthi, Wtlo);
        conv_split<<<convGrid, blk, 0, stream>>>(query, tAhi, tAlo);
        gemm_one<<<gemmGrid, blk, 0, stream>>>(tAhi, tAlo, WqH, WqL, bq, 1,
                                               nullptr, Qh, Ql);
        conv_split<<<convGrid, blk, 0, stream>>>(keys, tAhi, tAlo);
        gemm_one<<<gemmGrid, blk, 0, stream>>>(tAhi, tAlo, WkH, WkL, bk, 1,
                                               nullptr, Kh, Kl);
        conv_split<<<convGrid, blk, 0, stream>>>(values, tAhi, tAlo);
        gemm_one<<<gemmGrid, blk, 0, stream>>>(tAhi, tAlo, WvH, WvL, bv, 2,
                                               nullptr, Vbf, nullptr);
        v_transpose<<<dim3(16, NHEADS, NB), blk, 0, stream>>>(Vbf, Vtb);
        attn_mfma<<<dim3(SEQ / 128, NHEADS, NB), blk, 0, stream>>>(
            Qh, Ql, Kh, Kl, Vtb, mask, AoHi, AoLo);
        gemm_one<<<gemmGrid, blk, 0, stream>>>(AoHi, AoLo, WoH, WoL, bo, 0,
                                               out, nullptr, nullptr);
    }
}

// Round 7
// 504.588 us; speedup vs baseline: 1.8815x; 1.1024x over previous
//
#include <hip/hip_runtime.h>

// Problem constants
#define DM     1024
#define NHEADS 16
#define DK     64
#define NB     8
#define SEQ    1024
#define MROWS  (NB * SEQ)            // 8192
#define NQ     ((size_t)MROWS * DM)  // 8M elements

typedef unsigned short u16;
typedef __attribute__((ext_vector_type(8))) _Float16 f16x8;
typedef __attribute__((ext_vector_type(8))) short  short8v;
typedef __attribute__((ext_vector_type(4))) float  f32x4;

typedef const __attribute__((address_space(1))) void* gas_ptr;
typedef __attribute__((address_space(3))) void*       las_ptr;

__device__ __forceinline__ void load_lds16(const void* g, void* l) {
    __builtin_amdgcn_global_load_lds((gas_ptr)g, (las_ptr)l, 16, 0, 0);
}
__device__ __forceinline__ void load_lds4(const void* g, void* l) {
    __builtin_amdgcn_global_load_lds((gas_ptr)g, (las_ptr)l, 4, 0, 0);
}

__device__ __forceinline__ u16 f16_bits(float x) {
    union { _Float16 h; u16 u; } c;
    c.h = (_Float16)x;  // v_cvt_f16_f32, RNE
    return c.u;
}
__device__ __forceinline__ float f16_val(u16 u) {
    union { _Float16 h; u16 u; } c;
    c.u = u;
    return (float)c.h;
}

// ---------------------------------------------------------------------------
// conv_cast3: q,k,v fp32 -> single f16 (the split lives on the weight side).
// ---------------------------------------------------------------------------
__global__ __launch_bounds__(256)
void conv_cast3(const float* __restrict__ q, const float* __restrict__ k,
                const float* __restrict__ v, u16* __restrict__ qo,
                u16* __restrict__ ko, u16* __restrict__ vo)
{
    const int z = blockIdx.z;
    const float* in = (z == 0) ? q : (z == 1) ? k : v;
    u16* o = (z == 0) ? qo : (z == 1) ? ko : vo;
    size_t i8 = ((size_t)blockIdx.x * 256 + threadIdx.x) * 8;
    float4 x0 = *(const float4*)(in + i8);
    float4 x1 = *(const float4*)(in + i8 + 4);
    float xs[8] = {x0.x, x0.y, x0.z, x0.w, x1.x, x1.y, x1.z, x1.w};
    short8v r;
#pragma unroll
    for (int j = 0; j < 8; ++j) r[j] = (short)f16_bits(xs[j]);
    *(short8v*)(o + i8) = r;
}

// ---------------------------------------------------------------------------
// conv_w: W [k][n] fp32 -> Wt hi/lo [n][k] f16 (transposed split), 4 weights.
// ---------------------------------------------------------------------------
__global__ __launch_bounds__(256)
void conv_w(const float* __restrict__ W0, const float* __restrict__ W1,
            const float* __restrict__ W2, const float* __restrict__ W3,
            u16* __restrict__ hiB, u16* __restrict__ loB)
{
    __shared__ float Wf[32][68];
    const int t = threadIdx.x;
    const int n0 = blockIdx.x * 64, k0 = blockIdx.y * 32, z = blockIdx.z;
    const float* W = (z == 0) ? W0 : (z == 1) ? W1 : (z == 2) ? W2 : W3;
    u16* hi = hiB + (size_t)z * DM * DM;
    u16* lo = loB + (size_t)z * DM * DM;

#pragma unroll
    for (int p = 0; p < 2; ++p) {
        int fid = p * 256 + t;
        int kk = fid >> 4, c4 = fid & 15;
        *(float4*)&Wf[kk][c4 * 4] =
            *(const float4*)(W + (size_t)(k0 + kk) * DM + n0 + c4 * 4);
    }
    __syncthreads();

    const int n = t >> 2, g = t & 3;
    short8v vh, vl;
#pragma unroll
    for (int j = 0; j < 8; ++j) {
        float x = Wf[g * 8 + j][n];
        u16 h = f16_bits(x);
        vh[j] = (short)h;
        vl[j] = (short)f16_bits(x - f16_val(h));
    }
    size_t off = (size_t)(n0 + n) * DM + k0 + g * 8;
    *(short8v*)(hi + off) = vh;
    *(short8v*)(lo + off) = vl;
}

// ---------------------------------------------------------------------------
// 2-product f16 MFMA GEMM: C = A_f16 @ (B_hi + B_lo)^T + bias.
// A f16 [m][k], B hi/lo f16 [n][k]. 128x128 tile, 4 waves, BK=32.
// Modes: 0 = fp32 out (direct); 1 = f16 hi/lo pair (LDS-bounced, coalesced);
// 2 = single f16 (bounced); 3 = single f16 TRANSPOSED to Vt[b,h,d,s].
// smem layout: staging Af|Bh|Bl (24 KB) in K-loop; epilogue reuses all of it
// as a [128][136] u16 bounce tile (34 KB total) after a barrier.
// ---------------------------------------------------------------------------
#define PITCH 136
__device__ __forceinline__ void gemm2_body(
    const u16* __restrict__ Ag, const u16* __restrict__ Bgh,
    const u16* __restrict__ Bgl, const float* __restrict__ bias, int mode,
    float* __restrict__ Cf, u16* __restrict__ C1, u16* __restrict__ C2)
{
    __shared__ __align__(16) u16 smem[128 * PITCH];  // 34 KB
    u16* const Af = smem;          // 4096 u16
    u16* const Bh = smem + 4096;
    u16* const Bl = smem + 8192;

    const int t = threadIdx.x, lane = t & 63, wid = t >> 6;
    const int m0 = blockIdx.x * 128, n0 = blockIdx.y * 128;
    const int wm0 = (wid >> 1) * 64, wn0 = (wid & 1) * 64;
    const int ln = lane & 15, blk = lane >> 4;

    // staging: 24 one-KB chunks (Af:8, Bh:8, Bl:8), 6 per wave.
    const int lr = lane >> 2, sl = lane & 3;
    const int gg = sl ^ ((lr >> 1) & 3);  // source-side XOR swizzle
    const u16* gA[6];
    u16* lA[6];
#pragma unroll
    for (int i = 0; i < 6; ++i) {
        int c = wid * 6 + i, sub = c & 7;
        const u16* gsrc; u16* lbuf; int r0;
        if (c < 8)       { gsrc = Ag;  lbuf = Af; r0 = m0; }
        else if (c < 16) { gsrc = Bgh; lbuf = Bh; r0 = n0; }
        else             { gsrc = Bgl; lbuf = Bl; r0 = n0; }
        gA[i] = gsrc + (size_t)(r0 + sub * 16 + lr) * DM + gg * 8;
        lA[i] = lbuf + sub * 512;
    }

    f32x4 zero4 = {0.f, 0.f, 0.f, 0.f};
    f32x4 acc[4][4];
#pragma unroll
    for (int i = 0; i < 4; ++i)
#pragma unroll
        for (int j = 0; j < 4; ++j) acc[i][j] = zero4;

    for (int kt = 0; kt < 1024; kt += 32) {
        __syncthreads();
#pragma unroll
        for (int i = 0; i < 6; ++i) load_lds16(gA[i] + kt, lA[i]);
        __syncthreads();

        f16x8 bh[4], bl[4];
#pragma unroll
        for (int bn = 0; bn < 4; ++bn) {
            int rn = wn0 + bn * 16 + ln;
            int off = rn * 32 + ((blk ^ ((rn >> 1) & 3)) << 3);
            bh[bn] = *(const f16x8*)(Bh + off);
            bl[bn] = *(const f16x8*)(Bl + off);
        }
#pragma unroll
        for (int am = 0; am < 4; ++am) {
            int rm = wm0 + am * 16 + ln;
            int off = rm * 32 + ((blk ^ ((rm >> 1) & 3)) << 3);
            f16x8 af = *(const f16x8*)(Af + off);
#pragma unroll
            for (int bn = 0; bn < 4; ++bn) {
                acc[am][bn] = __builtin_amdgcn_mfma_f32_16x16x32_f16(
                    af, bh[bn], acc[am][bn], 0, 0, 0);
                acc[am][bn] = __builtin_amdgcn_mfma_f32_16x16x32_f16(
                    af, bl[bn], acc[am][bn], 0, 0, 0);
            }
        }
    }

    // ---- epilogue (C/D layout: col = lane&15, row = (lane>>4)*4 + reg) ----
    if (mode == 0) {
#pragma unroll
        for (int bn = 0; bn < 4; ++bn) {
            int coll = wn0 + bn * 16 + ln;
            float bs = bias[n0 + coll];
#pragma unroll
            for (int am = 0; am < 4; ++am)
#pragma unroll
                for (int r = 0; r < 4; ++r) {
                    int rowl = wm0 + am * 16 + blk * 4 + r;
                    Cf[(size_t)(m0 + rowl) * DM + n0 + coll] =
                        acc[am][bn][r] + bs;
                }
        }
        return;
    }

    __syncthreads();  // K-loop LDS reads done before smem reuse

    if (mode == 3) {
        // store TRANSPOSED into smem[col][row]; write Vt[b,h,d,s] coalesced
#pragma unroll
        for (int bn = 0; bn < 4; ++bn) {
            int coll = wn0 + bn * 16 + ln;
            float bs = bias[n0 + coll];
#pragma unroll
            for (int am = 0; am < 4; ++am)
#pragma unroll
                for (int r = 0; r < 4; ++r) {
                    int rowl = wm0 + am * 16 + blk * 4 + r;
                    smem[coll * PITCH + rowl] = f16_bits(acc[am][bn][r] + bs);
                }
        }
        __syncthreads();
        const int bq_ = m0 >> 10, s0_ = m0 & 1023, h0_ = n0 >> 6;
#pragma unroll
        for (int p = 0; p < 8; ++p) {
            int c = p * 256 + t;           // 0..2047
            int h_l = c >> 10;             // 0..1
            int d   = (c >> 4) & 63;
            int sc  = c & 15;
            int scp = (sc + ((d & 3) << 2)) & 15;  // bank de-phase
            short8v rd = *(const short8v*)(smem + (h_l * 64 + d) * PITCH +
                                           scp * 8);
            *(short8v*)(C1 +
                        ((size_t)(bq_ * NHEADS + h0_ + h_l) * DK + d) * SEQ +
                        s0_ + scp * 8) = rd;
        }
        return;
    }

    // modes 1/2: natural layout bounce; mode 1 keeps residual for the lo pass
#pragma unroll
    for (int bn = 0; bn < 4; ++bn) {
        int coll = wn0 + bn * 16 + ln;
        float bs = bias[n0 + coll];
#pragma unroll
        for (int am = 0; am < 4; ++am)
#pragma unroll
            for (int r = 0; r < 4; ++r) {
                int rowl = wm0 + am * 16 + blk * 4 + r;
                float v = acc[am][bn][r] + bs;
                u16 hb = f16_bits(v);
                smem[rowl * PITCH + coll] = hb;
                acc[am][bn][r] = v - f16_val(hb);  // residual
            }
    }
    __syncthreads();
#pragma unroll
    for (int p = 0; p < 8; ++p) {
        int f = p * 256 + t;
        int row = f >> 4, cc = f & 15;
        int ccp = (cc + ((row & 3) << 2)) & 15;
        short8v rd = *(const short8v*)(smem + row * PITCH + ccp * 8);
        *(short8v*)(C1 + (size_t)(m0 + row) * DM + n0 + ccp * 8) = rd;
    }
    if (mode == 1) {
        __syncthreads();
#pragma unroll
        for (int bn = 0; bn < 4; ++bn) {
            int coll = wn0 + bn * 16 + ln;
#pragma unroll
            for (int am = 0; am < 4; ++am)
#pragma unroll
                for (int r = 0; r < 4; ++r) {
                    int rowl = wm0 + am * 16 + blk * 4 + r;
                    smem[rowl * PITCH + coll] = f16_bits(acc[am][bn][r]);
                }
        }
        __syncthreads();
#pragma unroll
        for (int p = 0; p < 8; ++p) {
            int f = p * 256 + t;
            int row = f >> 4, cc = f & 15;
            int ccp = (cc + ((row & 3) << 2)) & 15;
            short8v rd = *(const short8v*)(smem + row * PITCH + ccp * 8);
            *(short8v*)(C2 + (size_t)(m0 + row) * DM + n0 + ccp * 8) = rd;
        }
    }
}

__global__ __launch_bounds__(256)
void gemm_qkv(const u16* __restrict__ Aq, const u16* __restrict__ Ak,
              const u16* __restrict__ Av, const u16* __restrict__ Wqh,
              const u16* __restrict__ Wql, const u16* __restrict__ Wkh,
              const u16* __restrict__ Wkl, const u16* __restrict__ Wvh,
              const u16* __restrict__ Wvl, const float* __restrict__ bq,
              const float* __restrict__ bk, const float* __restrict__ bv,
              u16* __restrict__ Qh, u16* __restrict__ Ql,
              u16* __restrict__ Kf, u16* __restrict__ Vt)
{
    const int z = blockIdx.z;
    const u16* A  = (z == 0) ? Aq  : (z == 1) ? Ak  : Av;
    const u16* Bh = (z == 0) ? Wqh : (z == 1) ? Wkh : Wvh;
    const u16* Bl = (z == 0) ? Wql : (z == 1) ? Wkl : Wvl;
    const float* bias = (z == 0) ? bq : (z == 1) ? bk : bv;
    u16* C1 = (z == 0) ? Qh : (z == 1) ? Kf : Vt;
    u16* C2 = (z == 0) ? Ql : nullptr;
    gemm2_body(A, Bh, Bl, bias, (z == 0) ? 1 : (z == 1) ? 2 : 3,
               nullptr, C1, C2);
}

__global__ __launch_bounds__(256)
void gemm_o(const u16* __restrict__ A, const u16* __restrict__ Bh,
            const u16* __restrict__ Bl, const float* __restrict__ bias,
            float* __restrict__ out)
{
    gemm2_body(A, Bh, Bl, bias, 0, out, nullptr, nullptr);
}

// ---------------------------------------------------------------------------
// attn_f16: flash attention on f16 MFMA. Q hi/lo in REGISTERS; K single f16 +
// V^T single f16 staged in LDS (source-XOR swizzled); QK^T = 2 products
// (qh·k + ql·k); defer-max online softmax with the 1/32 scale folded into
// exp; P in f16; epilogue LDS-bounced to coalesced short8 f16 stores.
// 128 q-rows/block, 4 waves x 32 q, KV tiles of 64. LDS ~25 KB.
// ---------------------------------------------------------------------------
#define OPITCH 72
__global__ __launch_bounds__(256)
void attn_f16(const u16* __restrict__ Qh, const u16* __restrict__ Ql,
              const u16* __restrict__ Kf, const u16* __restrict__ Vtg,
              const int* __restrict__ mask, u16* __restrict__ Ao)
{
    __shared__ __align__(16) u16 asmem[12288];  // Ks|Vts|Ps; epi bounce 128x72
    __shared__ int msk_s[64];
    u16* const Ks  = asmem;           // 4096 u16
    u16* const Vts = asmem + 4096;    // 4096 u16

    const int t = threadIdx.x, lane = t & 63, wid = t >> 6;
    const int q0 = blockIdx.x * 128;
    const int h = blockIdx.y, b = blockIdx.z;
    const int ln = lane & 15, blk = lane >> 4;
    const int lr8 = lane >> 3;
    const int schk = (lane & 7) ^ lr8;

    // ---- Q fragments (hi/lo f16) straight to registers ----
    f16x8 qfh[2][2], qfl[2][2];
#pragma unroll
    for (int am = 0; am < 2; ++am) {
        int row = q0 + wid * 32 + am * 16 + ln;
        size_t base = (size_t)(b * SEQ + row) * DM + h * DK;
#pragma unroll
        for (int ks = 0; ks < 2; ++ks) {
            qfh[am][ks] = *(const f16x8*)(Qh + base + (ks * 4 + blk) * 8);
            qfl[am][ks] = *(const f16x8*)(Ql + base + (ks * 4 + blk) * 8);
        }
    }

    // ---- staging plan: 16 chunks (Ks:8, Vts:8), 4 per wave ----
    const u16* gA[4];
    u16* lA[4];
    size_t stp[4];
#pragma unroll
    for (int i = 0; i < 4; ++i) {
        int c = wid * 4 + i, sub = c & 7;
        if (c < 8) {
            gA[i] = Kf + ((size_t)(b * SEQ) + sub * 8 + lr8) * DM + h * DK +
                    schk * 8;
            lA[i] = Ks + sub * 512;
            stp[i] = (size_t)64 * DM;
        } else {
            gA[i] = Vtg + ((size_t)((b * NHEADS + h) * DK) + sub * 8 + lr8) *
                              SEQ +
                    schk * 8;
            lA[i] = Vts + sub * 512;
            stp[i] = 64;
        }
    }

    float m_i[2][4], l_i[2][4];
    f32x4 oacc[2][4];
    f32x4 zero4 = {0.f, 0.f, 0.f, 0.f};
#pragma unroll
    for (int am = 0; am < 2; ++am) {
#pragma unroll
        for (int r = 0; r < 4; ++r) { m_i[am][r] = -INFINITY; l_i[am][r] = 0.f; }
#pragma unroll
        for (int bn = 0; bn < 4; ++bn) oacc[am][bn] = zero4;
    }

    for (int kv0 = 0; kv0 < SEQ; kv0 += 64) {
        __syncthreads();
#pragma unroll
        for (int i = 0; i < 4; ++i) {
            load_lds16(gA[i], lA[i]);
            gA[i] += stp[i];
        }
        if (wid == 3)
            load_lds4(mask + (size_t)b * SEQ + kv0 + lane, (char*)msk_s);
        __syncthreads();

        int mvals[4];
#pragma unroll
        for (int ct = 0; ct < 4; ++ct) mvals[ct] = msk_s[ct * 16 + ln];

#pragma unroll
        for (int am = 0; am < 2; ++am) {
            // ---- QK^T: 2 products (qh·k + ql·k) ----
            f32x4 s[4];
#pragma unroll
            for (int ct = 0; ct < 4; ++ct) s[ct] = zero4;
#pragma unroll
            for (int ct = 0; ct < 4; ++ct) {
                int krow = ct * 16 + ln;
#pragma unroll
                for (int ks = 0; ks < 2; ++ks) {
                    int idx = krow * 64 + (((ks * 4 + blk) ^ (krow & 7)) << 3);
                    f16x8 kf = *(const f16x8*)(Ks + idx);
                    s[ct] = __builtin_amdgcn_mfma_f32_16x16x32_f16(
                        qfh[am][ks], kf, s[ct], 0, 0, 0);
                    s[ct] = __builtin_amdgcn_mfma_f32_16x16x32_f16(
                        qfl[am][ks], kf, s[ct], 0, 0, 0);
                }
            }
            // mask on raw scores (scale folded into exp below)
#pragma unroll
            for (int ct = 0; ct < 4; ++ct) {
                if (mvals[ct] == 0) {
#pragma unroll
                    for (int r = 0; r < 4; ++r) s[ct][r] = -1e20f;
                }
            }
            // online softmax, defer-max (THR=8 in scaled space)
#pragma unroll
            for (int r = 0; r < 4; ++r) {
                float mt = fmaxf(fmaxf(s[0][r], s[1][r]),
                                 fmaxf(s[2][r], s[3][r]));
#pragma unroll
                for (int off = 1; off < 16; off <<= 1)
                    mt = fmaxf(mt, __shfl_xor(mt, off, 16));
                float pmax = mt * 0.03125f;
                if (pmax > m_i[am][r] + 8.f) {
                    float al = __expf(m_i[am][r] - pmax);
                    m_i[am][r] = pmax;
                    l_i[am][r] *= al;
#pragma unroll
                    for (int bn = 0; bn < 4; ++bn) oacc[am][bn][r] *= al;
                }
                float mn = m_i[am][r];
                float rs = 0.f;
#pragma unroll
                for (int ct = 0; ct < 4; ++ct) {
                    float p = __expf(fmaf(s[ct][r], 0.03125f, -mn));
                    s[ct][r] = p;
                    rs += p;
                }
#pragma unroll
                for (int off = 1; off < 16; off <<= 1)
                    rs += __shfl_xor(rs, off, 16);
                l_i[am][r] += rs;
            }
            // ---- P -> f16 -> wave-private LDS (swizzled slots) ----
            u16* P = asmem + 8192 + wid * 1024;
#pragma unroll
            for (int ct = 0; ct < 4; ++ct) {
                int slot = ct * 2 + (ln >> 3);
#pragma unroll
                for (int r = 0; r < 4; ++r) {
                    int q = blk * 4 + r;
                    P[q * 64 + ((slot ^ (q & 7)) << 3) + (ln & 7)] =
                        f16_bits(s[ct][r]);
                }
            }
            // ---- PV: O += P @ V^T (single product) ----
#pragma unroll
            for (int ks = 0; ks < 2; ++ks) {
                int pidx = ln * 64 + (((ks * 4 + blk) ^ (ln & 7)) << 3);
                f16x8 pa = *(const f16x8*)(P + pidx);
#pragma unroll
                for (int bn = 0; bn < 4; ++bn) {
                    int vrow = bn * 16 + ln;
                    int vidx =
                        vrow * 64 + (((ks * 4 + blk) ^ (vrow & 7)) << 3);
                    f16x8 vb = *(const f16x8*)(Vts + vidx);
                    oacc[am][bn] = __builtin_amdgcn_mfma_f32_16x16x32_f16(
                        pa, vb, oacc[am][bn], 0, 0, 0);
                }
            }
        }
    }

    // ---- epilogue: normalize, f16, LDS-bounce to coalesced stores ----
    __syncthreads();
#pragma unroll
    for (int am = 0; am < 2; ++am) {
#pragma unroll
        for (int r = 0; r < 4; ++r) {
            int ql_ = wid * 32 + am * 16 + blk * 4 + r;
            float inv = 1.f / l_i[am][r];
#pragma unroll
            for (int bn = 0; bn < 4; ++bn) {
                int d = bn * 16 + ln;
                asmem[ql_ * OPITCH + d] = f16_bits(oacc[am][bn][r] * inv);
            }
        }
    }
    __syncthreads();
#pragma unroll
    for (int p = 0; p < 4; ++p) {
        int f = p * 256 + t;
        int qq = f >> 3, dc = f & 7;
        short8v rd = *(const short8v*)(asmem + qq * OPITCH + dc * 8);
        *(short8v*)(Ao + (size_t)(b * SEQ + q0 + qq) * DM + h * DK + dc * 8) =
            rd;
    }
}

// ---------------------------------------------------------------------------
extern "C" void kernel_launch(void* const* d_in, const int* in_sizes, int n_in,
                              void* d_out, int out_size, void* d_ws, size_t ws_size,
                              hipStream_t stream)
{
    const float* values = (const float*)d_in[0];
    const float* keys   = (const float*)d_in[1];
    const float* query  = (const float*)d_in[2];
    const int*   mask   = (const int*)d_in[3];
    const float* Wq = (const float*)d_in[4];
    const float* bq = (const float*)d_in[5];
    const float* Wk = (const float*)d_in[6];
    const float* bk = (const float*)d_in[7];
    const float* Wv = (const float*)d_in[8];
    const float* bv = (const float*)d_in[9];
    const float* Wo = (const float*)d_in[10];
    const float* bo = (const float*)d_in[11];
    float* out = (float*)d_out;

    // workspace (u16 units), 144 MB total
    u16* Qh   = (u16*)d_ws;                  // 16 MB
    u16* Ql   = Qh + NQ;                     // 16 MB
    u16* Kf   = Ql + NQ;                     // 16 MB
    u16* Vt   = Kf + NQ;                     // 16 MB
    u16* Wthi = Vt + NQ;                     // 8 MB (4 x [n][k] f16)
    u16* Wtlo = Wthi + (size_t)4 * DM * DM;  // 8 MB
    u16* tAq  = Wtlo + (size_t)4 * DM * DM;  // 16 MB
    u16* tAk  = tAq + NQ;                    // 16 MB
    u16* tAv  = tAk + NQ;                    // 16 MB
    u16* Ao   = tAv + NQ;                    // 16 MB

    const u16* WqH = Wthi + 0 * (size_t)DM * DM;
    const u16* WkH = Wthi + 1 * (size_t)DM * DM;
    const u16* WvH = Wthi + 2 * (size_t)DM * DM;
    const u16* WoH = Wthi + 3 * (size_t)DM * DM;
    const u16* WqL = Wtlo + 0 * (size_t)DM * DM;
    const u16* WkL = Wtlo + 1 * (size_t)DM * DM;
    const u16* WvL = Wtlo + 2 * (size_t)DM * DM;
    const u16* WoL = Wtlo + 3 * (size_t)DM * DM;

    dim3 blk(256);
    conv_w<<<dim3(16, 32, 4), blk, 0, stream>>>(Wq, Wk, Wv, Wo, Wthi, Wtlo);
    conv_cast3<<<dim3((int)(NQ / 2048), 1, 3), blk, 0, stream>>>(
        query, keys, values, tAq, tAk, tAv);
    gemm_qkv<<<dim3(MROWS / 128, DM / 128, 3), blk, 0, stream>>>(
        tAq, tAk, tAv, WqH, WqL, WkH, WkL, WvH, WvL, bq, bk, bv,
        Qh, Ql, Kf, Vt);
    attn_f16<<<dim3(SEQ / 128, NHEADS, NB), blk, 0, stream>>>(
        Qh, Ql, Kf, Vt, mask, Ao);
    gemm_o<<<dim3(MROWS / 128, DM / 128, 1), blk, 0, stream>>>(
        Ao, WoH, WoL, bo, out);
}